// Round 4
// baseline (1601.356 us; speedup 1.0000x reference)
//
#include <hip/hip_runtime.h>
#include <hip/hip_bf16.h>
#include <math.h>

#define IGNORE_INDEX (-100)

constexpr int N = 8192;
constexpr int D = 1024;
constexpr int V = 50257;

constexpr int BM = 128;
constexpr int BN = 256;
constexpr int BK = 128;                  // one 16x16x128 MFMA K-depth per ks
constexpr int NC = 16;                   // V-chunks (grid.x)
constexpr int SUBT = (V + BN - 1) / BN;  // 197 column tiles

constexpr float LOG2E = 1.44269504088896340736f;
constexpr float LN2 = 0.69314718055994530942f;

typedef __attribute__((ext_vector_type(8))) int int8v;
typedef __attribute__((ext_vector_type(4))) float floatx4;

__device__ __forceinline__ void gload_lds16(const void* g, void* l) {
  __builtin_amdgcn_global_load_lds(
      (const __attribute__((address_space(1))) void*)g,
      (__attribute__((address_space(3))) void*)l, 16, 0, 0);
}

__device__ __forceinline__ float fexp2(float x) {
#if __has_builtin(__builtin_amdgcn_exp2f)
  return __builtin_amdgcn_exp2f(x);
#else
  return exp2f(x);
#endif
}

// ---------------- prep: fp8(e4m3, OCP) casts + exact fp32 target dot --------
// e is pre-scaled by log2(e) so the GEMM computes base-2 logits.
constexpr int E8 = N * D / 8;         // 8-float work items for e
constexpr int C8 = V * D / 8;         // for c
constexpr int EB = E8 / 256;          // 4096 blocks (exact)
constexpr int CB = (C8 + 255) / 256;  // 25129 blocks
constexpr int TGT_BLOCKS = N / 4;     // 2048 blocks

__device__ __forceinline__ unsigned int pk4_fp8(float a, float b, float c,
                                                float d) {
  int p = __builtin_amdgcn_cvt_pk_fp8_f32(a, b, 0, false);
  p = __builtin_amdgcn_cvt_pk_fp8_f32(c, d, p, true);
  return (unsigned int)p;
}

__global__ void prep_kernel(const float* __restrict__ e,
                            const float* __restrict__ c,
                            const int* __restrict__ t,
                            unsigned int* __restrict__ e8,
                            unsigned int* __restrict__ c8,
                            float* __restrict__ tgt) {
  const int b = blockIdx.x;
  if (b < EB) {
    const int idx = b * 256 + threadIdx.x;  // one 8-float unit
    const float4 v0 = ((const float4*)e)[idx * 2];
    const float4 v1 = ((const float4*)e)[idx * 2 + 1];
    uint2 o;
    o.x = pk4_fp8(v0.x * LOG2E, v0.y * LOG2E, v0.z * LOG2E, v0.w * LOG2E);
    o.y = pk4_fp8(v1.x * LOG2E, v1.y * LOG2E, v1.z * LOG2E, v1.w * LOG2E);
    ((uint2*)e8)[idx] = o;
  } else if (b < EB + CB) {
    const int idx = (b - EB) * 256 + threadIdx.x;
    if (idx < C8) {
      const float4 v0 = ((const float4*)c)[idx * 2];
      const float4 v1 = ((const float4*)c)[idx * 2 + 1];
      uint2 o;
      o.x = pk4_fp8(v0.x, v0.y, v0.z, v0.w);
      o.y = pk4_fp8(v1.x, v1.y, v1.z, v1.w);
      ((uint2*)c8)[idx] = o;
    }
  } else {
    const int row = (b - EB - CB) * 4 + (threadIdx.x >> 6);
    const int lane = threadIdx.x & 63;
    int tr = t[row];
    if (tr == IGNORE_INDEX) tr = 0;
    const float4* ev = (const float4*)(e + (size_t)row * D);
    const float4* cv = (const float4*)(c + (size_t)tr * D);
    float s = 0.f;
#pragma unroll
    for (int k = 0; k < 4; ++k) {
      float4 a = ev[lane + k * 64];
      float4 bb = cv[lane + k * 64];
      s += a.x * bb.x + a.y * bb.y + a.z * bb.z + a.w * bb.w;
    }
#pragma unroll
    for (int d = 1; d < 64; d <<= 1) s += __shfl_xor(s, d, 64);
    if (lane == 0) tgt[row] = s;
  }
}

// ---------------- fused fp8 GEMM + online logsumexp partials ----------------
// A = e_fp8 (log2e-scaled) [N][D], B = c_fp8 [V][D], K-major bytes.
// MFMA: 16x16x128 f8f6f4, fmt=fp8 both, scales fixed to 1 (all bytes 0x7F).
//
// Counted-vmcnt schedule (T3/T4): per step g
//   1. issue stage(g+1) -> smB[cur^1]   (8 global_load_lds; reads of that
//      buffer were closed by the previous step's barrier-2)
//   2. issue A-prefetch(g+1) -> afn     (8 global_load_dwordx4)
//   3. s_waitcnt vmcnt(16)              (drains OWN stage(g)+A(g); keeps this
//      step's 16 in flight), then raw s_barrier: all waves' stage(g) landed
//   4. ds_read + 32 MFMA on smB[cur]    (setprio around the cluster)
//   5. lgkmcnt(0) + raw s_barrier       (closes reads of smB[cur] before any
//      wave stages into it at step g+1)
// No wait in the main loop ever drains to vmcnt(0): the staging latency spans
// the full MFMA cluster + 2 barriers (~2200 SIMD-cyc >> 900-cyc HBM miss).
// Race-freedom is by barrier pairing only, no timing assumptions.
// ks loop stays unroll(1): full unroll spilled acc (round-2: 17 GB scratch).
// Partials (m2, s2) in base-2 space: lse = ln2*(m2 + log2(s2)).
__global__ __launch_bounds__(256, 2) void gemm_lse_kernel(
    const unsigned char* __restrict__ A, const unsigned char* __restrict__ B,
    float* __restrict__ m_part, float* __restrict__ s_part) {
  __shared__ char smB[2][BN * BK];  // 2 x 32 KB, XOR-swizzled rows
  __shared__ float red_m[2][BM];
  __shared__ float red_s[2][BM];

  const int chunk = blockIdx.x;
  const int row0 = blockIdx.y * BM;
  const int tid = threadIdx.x;
  const int wave = tid >> 6;
  const int lane = tid & 63;
  const int wr = wave >> 1;  // row half (64 rows)
  const int wc = wave & 1;   // col half (128 cols)
  const int quad = lane >> 4;
  const int l16 = lane & 15;

  // B staging: lane's LDS slot fixed; source vec chosen so physical vec pv
  // holds logical vec pv ^ (row&7).
  const int lrow = lane >> 3;
  const int lvec_st = (lane & 7) ^ lrow;

  // A fragment base: row = row0 + wr*64 + i*16 + l16, k = quad*32 + 0..31
  const int4* abase =
      (const int4*)(A + (size_t)(row0 + wr * 64 + l16) * D + quad * 32);

  // per-thread online lse state: 16 (m,s) pairs
  float rm[16], rs[16];
#pragma unroll
  for (int x = 0; x < 16; ++x) { rm[x] = -1e30f; rs[x] = 0.0f; }

  const int nsub = (SUBT - chunk + NC - 1) / NC;  // round-robin col tiles

  auto stage = [&](int col0s, int kss, char* dst) {
#pragma unroll
    for (int cc = 0; cc < 8; ++cc) {
      const int ch = wave * 8 + cc;
      int brow = col0s + ch * 8 + lrow;
      if (brow >= V) brow = V - 1;  // clamp: harmless dup, masked in stats
      gload_lds16(B + (size_t)brow * D + kss * BK + lvec_st * 16,
                  dst + ch * 1024 + lane * 16);
    }
  };
  auto loadA = [&](int kss, int8v* af) {
#pragma unroll
    for (int i = 0; i < 4; ++i) {
      const int4 lo = abase[i * 1024 + kss * 8];
      const int4 hi = abase[i * 1024 + kss * 8 + 1];
      af[i][0] = lo.x; af[i][1] = lo.y; af[i][2] = lo.z; af[i][3] = lo.w;
      af[i][4] = hi.x; af[i][5] = hi.y; af[i][6] = hi.z; af[i][7] = hi.w;
    }
  };

  // ---- prologue: issue stage(0) + A(0); NOT waited here (uniform count) ----
  stage(chunk * BN, 0, smB[0]);
  int8v af[4];
  loadA(0, af);

  int cur = 0;
  for (int si = 0; si < nsub; ++si) {
    const int col0 = (chunk + si * NC) * BN;
    floatx4 acc[4][8];
#pragma unroll
    for (int i = 0; i < 4; ++i)
#pragma unroll
      for (int j = 0; j < 8; ++j) acc[i][j] = floatx4{0.f, 0.f, 0.f, 0.f};

#pragma unroll 1  // keep body small: full unroll spills acc (round-2 lesson)
    for (int ks = 0; ks < D / BK; ++ks) {
      const int ksn = (ks + 1) & 7;
      const int col0n = (ks == 7) ? col0 + NC * BN : col0;

      // ---- 1+2. issue next step's B staging and A prefetch (16 VMEM) ----
      // Last step's issues are harmless clamped prefetches (keeps count=16).
      stage(col0n, ksn, smB[cur ^ 1]);
      int8v afn[4];
      loadA(ksn, afn);

      // ---- 3. counted drain + barrier-1: smB[cur] globally ready ----
      __builtin_amdgcn_sched_barrier(0);  // pin all 16 issues above the wait
      asm volatile("s_waitcnt vmcnt(16)" ::: "memory");
      __builtin_amdgcn_sched_barrier(0);
      __builtin_amdgcn_s_barrier();

      // ---- 4. compute on current buffer ----
      const char* bufR = smB[cur];
#pragma unroll
      for (int jh = 0; jh < 2; ++jh) {  // halves cap live bf regs at 32
        int8v bf[4];
#pragma unroll
        for (int jj = 0; jj < 4; ++jj) {
          const int cr = wc * 128 + (jh * 4 + jj) * 16 + l16;
          const char* base = bufR + cr * 128;
          const int4 lo =
              *(const int4*)(base + (((quad * 2) ^ (cr & 7)) * 16));
          const int4 hi =
              *(const int4*)(base + (((quad * 2 + 1) ^ (cr & 7)) * 16));
          bf[jj][0] = lo.x; bf[jj][1] = lo.y; bf[jj][2] = lo.z; bf[jj][3] = lo.w;
          bf[jj][4] = hi.x; bf[jj][5] = hi.y; bf[jj][6] = hi.z; bf[jj][7] = hi.w;
        }
        __builtin_amdgcn_s_setprio(1);
#pragma unroll
        for (int jj = 0; jj < 4; ++jj)
#pragma unroll
          for (int i = 0; i < 4; ++i)
            acc[i][jh * 4 + jj] =
                __builtin_amdgcn_mfma_scale_f32_16x16x128_f8f6f4(
                    af[i], bf[jj], acc[i][jh * 4 + jj], 0, 0,  // fp8 both
                    0, 0x7F7F7F7F, 0, 0x7F7F7F7F);             // scales = 2^0
        __builtin_amdgcn_s_setprio(0);
      }

      // ---- 5. rotate A regs; barrier-2 closes reads of smB[cur] ----
#pragma unroll
      for (int i = 0; i < 4; ++i) af[i] = afn[i];
      if (ks != 7) {
        asm volatile("s_waitcnt lgkmcnt(0)" ::: "memory");  // LDS reads done
        __builtin_amdgcn_sched_barrier(0);
        __builtin_amdgcn_s_barrier();
      }
      cur ^= 1;
    }

    // ---- per-tile online update (overlaps the in-flight prefetches) ----
    {
      const bool edge = (col0 + BN > V);  // wave-uniform (last tile only)
#pragma unroll
      for (int i = 0; i < 4; ++i) {
#pragma unroll
        for (int reg = 0; reg < 4; ++reg) {
          float v[8];
#pragma unroll
          for (int j = 0; j < 8; ++j) v[j] = acc[i][j][reg];
          if (edge) {
            const int cb = col0 + wc * 128 + l16;
#pragma unroll
            for (int j = 0; j < 8; ++j)
              if (cb + j * 16 >= V) v[j] = -INFINITY;
          }
          float mx = v[0];
#pragma unroll
          for (int j = 1; j < 8; ++j) mx = fmaxf(mx, v[j]);
          const int x = i * 4 + reg;
          const float nm = fmaxf(rm[x], mx);
          float s = rs[x] * fexp2(rm[x] - nm);
#pragma unroll
          for (int j = 0; j < 8; ++j) s += fexp2(v[j] - nm);
          rs[x] = s;
          rm[x] = nm;
        }
      }
    }
    // barrier-2 for the tile's last step (reads of its buffer now closed)
    asm volatile("s_waitcnt lgkmcnt(0)" ::: "memory");
    __builtin_amdgcn_sched_barrier(0);
    __builtin_amdgcn_s_barrier();
  }

  // ---- once-per-kernel reduction: butterfly over 16 lanes per row ----
#pragma unroll
  for (int x = 0; x < 16; ++x) {
    float m = rm[x], s = rs[x];
#pragma unroll
    for (int d = 1; d < 16; d <<= 1) {
      const float om = __shfl_xor(m, d, 64);
      const float os = __shfl_xor(s, d, 64);
      const float nm = fmaxf(m, om);
      s = s * fexp2(m - nm) + os * fexp2(om - nm);
      m = nm;
    }
    if (l16 == 0) {
      const int i = x >> 2, reg = x & 3;
      const int rloc = wr * 64 + i * 16 + quad * 4 + reg;
      red_m[wc][rloc] = m;
      red_s[wc][rloc] = s;
    }
  }
  __syncthreads();  // full drain here is fine (once per kernel)
  if (tid < BM) {  // merge the two column-half waves, write chunk partials
    const float m0 = red_m[0][tid], s0 = red_s[0][tid];
    const float m1 = red_m[1][tid], s1 = red_s[1][tid];
    const float tm = fmaxf(m0, m1);
    const float ts = s0 * fexp2(m0 - tm) + s1 * fexp2(m1 - tm);
    m_part[(size_t)chunk * N + row0 + tid] = tm;
    s_part[(size_t)chunk * N + row0 + tid] = ts;
  }
}

// ---------------- finalize: merge chunk partials, subtract target, mean -----
__global__ void finalize1_kernel(const float* __restrict__ m_part,
                                 const float* __restrict__ s_part,
                                 const float* __restrict__ tgt,
                                 const int* __restrict__ t,
                                 double* __restrict__ fin) {
  const int tid = threadIdx.x;
  const int row = blockIdx.x * 256 + tid;
  float M = -1e30f;
#pragma unroll
  for (int ch = 0; ch < NC; ++ch) M = fmaxf(M, m_part[ch * N + row]);
  float S = 0.f;
#pragma unroll
  for (int ch = 0; ch < NC; ++ch)
    S += s_part[ch * N + row] * fexp2(m_part[ch * N + row] - M);
  const float lse = LN2 * (M + log2f(S));  // back to natural-log space
  double nll = 0.0;
  double cnt = 0.0;
  if (t[row] != IGNORE_INDEX) {
    nll = (double)(lse - tgt[row]);
    cnt = 1.0;
  }
  __shared__ double sacc[256];
  __shared__ double scnt[256];
  sacc[tid] = nll;
  scnt[tid] = cnt;
  __syncthreads();
  for (int s = 128; s > 0; s >>= 1) {
    if (tid < s) {
      sacc[tid] += sacc[tid + s];
      scnt[tid] += scnt[tid + s];
    }
    __syncthreads();
  }
  if (tid == 0) {
    fin[blockIdx.x * 2] = sacc[0];
    fin[blockIdx.x * 2 + 1] = scnt[0];
  }
}

__global__ void finalize2_kernel(const double* __restrict__ fin,
                                 float* __restrict__ out) {
  const int tid = threadIdx.x;  // 64 threads, 32 active
  __shared__ double sa[64], sc[64];
  sa[tid] = (tid < 32) ? fin[tid * 2] : 0.0;
  sc[tid] = (tid < 32) ? fin[tid * 2 + 1] : 0.0;
  __syncthreads();
  for (int s = 32; s > 0; s >>= 1) {
    if (tid < s) {
      sa[tid] += sa[tid + s];
      sc[tid] += sc[tid + s];
    }
    __syncthreads();
  }
  if (tid == 0) out[0] = (float)(sa[0] / fmax(sc[0], 1.0));
}

extern "C" void kernel_launch(void* const* d_in, const int* in_sizes, int n_in,
                              void* d_out, int out_size, void* d_ws,
                              size_t ws_size, hipStream_t stream) {
  const float* e = (const float*)d_in[0];
  const float* c = (const float*)d_in[1];
  const int* t = (const int*)d_in[2];
  float* out = (float*)d_out;

  char* ws = (char*)d_ws;
  unsigned char* e8 = (unsigned char*)ws;  // 8 MB (log2e-scaled fp8)
  size_t off = (size_t)N * D;
  unsigned char* c8 = (unsigned char*)(ws + off);  // 51.5 MB
  off += (size_t)V * D;
  off = (off + 255) & ~(size_t)255;
  float* tgt = (float*)(ws + off);
  off += (size_t)N * 4;
  float* m_part = (float*)(ws + off);
  off += (size_t)NC * N * 4;
  float* s_part = (float*)(ws + off);
  off += (size_t)NC * N * 4;
  double* fin = (double*)(ws + off);
  off += 32 * 2 * sizeof(double);  // total ~61 MB of d_ws

  prep_kernel<<<EB + CB + TGT_BLOCKS, 256, 0, stream>>>(
      e, c, t, (unsigned int*)e8, (unsigned int*)c8, tgt);
  gemm_lse_kernel<<<dim3(NC, N / BM), 256, 0, stream>>>(e8, c8, m_part,
                                                        s_part);
  finalize1_kernel<<<32, 256, 0, stream>>>(m_part, s_part, tgt, t, fin);
  finalize2_kernel<<<1, 64, 0, stream>>>(fin, out);
}

// Round 5
// 787.525 us; speedup vs baseline: 2.0334x; 2.0334x over previous
//
#include <hip/hip_runtime.h>
#include <hip/hip_bf16.h>
#include <math.h>

#define IGNORE_INDEX (-100)

constexpr int N = 8192;
constexpr int D = 1024;
constexpr int V = 50257;

constexpr int BM = 256;                  // block rows (8-wave block)
constexpr int BN = 256;                  // block cols
constexpr int BK = 128;                  // one 16x16x128 MFMA K-depth per ks
constexpr int NC = 16;                   // V-chunks (grid.x)
constexpr int SUBT = (V + BN - 1) / BN;  // 197 column tiles

constexpr float LOG2E = 1.44269504088896340736f;
constexpr float LN2 = 0.69314718055994530942f;

typedef __attribute__((ext_vector_type(8))) int int8v;
typedef __attribute__((ext_vector_type(4))) float floatx4;

__device__ __forceinline__ void gload_lds16(const void* g, void* l) {
  __builtin_amdgcn_global_load_lds(
      (const __attribute__((address_space(1))) void*)g,
      (__attribute__((address_space(3))) void*)l, 16, 0, 0);
}

__device__ __forceinline__ float fexp2(float x) {
#if __has_builtin(__builtin_amdgcn_exp2f)
  return __builtin_amdgcn_exp2f(x);
#else
  return exp2f(x);
#endif
}

// ---------------- prep: fp8(e4m3, OCP) casts + exact fp32 target dot --------
// e is pre-scaled by log2(e) so the GEMM computes base-2 logits.
constexpr int E8 = N * D / 8;         // 8-float work items for e
constexpr int C8 = V * D / 8;         // for c
constexpr int EB = E8 / 256;          // 4096 blocks (exact)
constexpr int CB = (C8 + 255) / 256;  // 25129 blocks
constexpr int TGT_BLOCKS = N / 4;     // 2048 blocks

__device__ __forceinline__ unsigned int pk4_fp8(float a, float b, float c,
                                                float d) {
  int p = __builtin_amdgcn_cvt_pk_fp8_f32(a, b, 0, false);
  p = __builtin_amdgcn_cvt_pk_fp8_f32(c, d, p, true);
  return (unsigned int)p;
}

__global__ void prep_kernel(const float* __restrict__ e,
                            const float* __restrict__ c,
                            const int* __restrict__ t,
                            unsigned int* __restrict__ e8,
                            unsigned int* __restrict__ c8,
                            float* __restrict__ tgt) {
  const int b = blockIdx.x;
  if (b < EB) {
    const int idx = b * 256 + threadIdx.x;  // one 8-float unit
    const float4 v0 = ((const float4*)e)[idx * 2];
    const float4 v1 = ((const float4*)e)[idx * 2 + 1];
    uint2 o;
    o.x = pk4_fp8(v0.x * LOG2E, v0.y * LOG2E, v0.z * LOG2E, v0.w * LOG2E);
    o.y = pk4_fp8(v1.x * LOG2E, v1.y * LOG2E, v1.z * LOG2E, v1.w * LOG2E);
    ((uint2*)e8)[idx] = o;
  } else if (b < EB + CB) {
    const int idx = (b - EB) * 256 + threadIdx.x;
    if (idx < C8) {
      const float4 v0 = ((const float4*)c)[idx * 2];
      const float4 v1 = ((const float4*)c)[idx * 2 + 1];
      uint2 o;
      o.x = pk4_fp8(v0.x, v0.y, v0.z, v0.w);
      o.y = pk4_fp8(v1.x, v1.y, v1.z, v1.w);
      ((uint2*)c8)[idx] = o;
    }
  } else {
    const int row = (b - EB - CB) * 4 + (threadIdx.x >> 6);
    const int lane = threadIdx.x & 63;
    int tr = t[row];
    if (tr == IGNORE_INDEX) tr = 0;
    const float4* ev = (const float4*)(e + (size_t)row * D);
    const float4* cv = (const float4*)(c + (size_t)tr * D);
    float s = 0.f;
#pragma unroll
    for (int k = 0; k < 4; ++k) {
      float4 a = ev[lane + k * 64];
      float4 bb = cv[lane + k * 64];
      s += a.x * bb.x + a.y * bb.y + a.z * bb.z + a.w * bb.w;
    }
#pragma unroll
    for (int d = 1; d < 64; d <<= 1) s += __shfl_xor(s, d, 64);
    if (lane == 0) tgt[row] = s;
  }
}

// ---------------- fused fp8 GEMM + online logsumexp partials ----------------
// A = e_fp8 (log2e-scaled) [N][D], B = c_fp8 [V][D], K-major bytes.
// MFMA: 16x16x128 f8f6f4, fmt=fp8 both, scales fixed to 1 (all bytes 0x7F).
//
// BOTH operands staged to LDS via global_load_lds (zero-VGPR prefetch — the
// unified VGPR/AGPR file leaves ~4 spare regs at 2 waves/SIMD; round 4's
// register A-prefetch spilled). 512-thread block, 256x256 tile, 8 waves of
// 64 rows x 128 cols each (per-wave shape identical to the proven round-3
// kernel). LDS: 2x32KB A + 2x32KB B (double-buffered) = 128 KB.
//
// Counted-vmcnt schedule (T3/T4): per step g each wave issues exactly 8
// gload_lds (4 B + 4 A — the loop has NO other VMEM, so the count is exact):
//   1. issue stage(g+1) -> {A,B}buf[cur^1]
//   2. s_waitcnt vmcnt(8)  (waits ONLY stage(g), issued a full step ago;
//      the 8 just-issued stay in flight), s_barrier: buf[cur] ready
//   3. ds_read af/bf + 32 MFMA (setprio around clusters)
//   4. lgkmcnt(0) + s_barrier (closes reads of buf[cur] before step g+1
//      stages into it)
// No vmcnt(0) drain in the loop; no A-latency exposure. Barrier pairing is
// isomorphic to round 3's (verified-passing) pairing. Tile boundaries are
// ordinary steps: the ks==7 stage targets the next tile's first buffer.
// ks loop stays unroll(1): full unroll spilled acc (round-2: 17 GB scratch).
// Partials (m2, s2) in base-2 space: lse = ln2*(m2 + log2(s2)).
__global__ __launch_bounds__(512, 2) void gemm_lse_kernel(
    const unsigned char* __restrict__ A, const unsigned char* __restrict__ B,
    float* __restrict__ m_part, float* __restrict__ s_part) {
  __shared__ char smA[2][BM * BK];  // 2 x 32 KB, XOR-swizzled rows
  __shared__ char smB[2][BN * BK];  // 2 x 32 KB, XOR-swizzled rows
  __shared__ float red_m[2][BM];
  __shared__ float red_s[2][BM];

  const int chunk = blockIdx.x;
  const int row0 = blockIdx.y * BM;
  const int tid = threadIdx.x;
  const int wave = tid >> 6;
  const int lane = tid & 63;
  const int wr = wave >> 1;  // row quarter (64 rows each, 4 groups)
  const int wc = wave & 1;   // col half (128 cols)
  const int quad = lane >> 4;
  const int l16 = lane & 15;

  // staging: lane's LDS slot fixed (chunk base + lane*16); source vec chosen
  // so physical vec pv holds logical vec pv ^ (row&7) (read-side XOR swizzle).
  const int lrow = lane >> 3;
  const int lvec_st = (lane & 7) ^ lrow;

  // per-thread online lse state: 16 (m,s) pairs
  float rm[16], rs[16];
#pragma unroll
  for (int x = 0; x < 16; ++x) { rm[x] = -1e30f; rs[x] = 0.0f; }

  const int nsub = (SUBT - chunk + NC - 1) / NC;  // round-robin col tiles

  // B: 256 rows x 8 vecs = 2048 slots of 16B; 512 threads x 4.  ch = 8-row
  // chunk index 0..31; each wave covers 4 chunks.
  auto stageB = [&](int col0s, int kss, char* dst) {
#pragma unroll
    for (int cc = 0; cc < 4; ++cc) {
      const int ch = wave * 4 + cc;
      int brow = col0s + ch * 8 + lrow;
      if (brow >= V) brow = V - 1;  // clamp: harmless dup, masked in stats
      gload_lds16(B + (size_t)brow * D + kss * BK + lvec_st * 16,
                  dst + ch * 1024 + lane * 16);
    }
  };
  auto stageA = [&](int kss, char* dst) {
#pragma unroll
    for (int cc = 0; cc < 4; ++cc) {
      const int ch = wave * 4 + cc;
      const int arow = row0 + ch * 8 + lrow;  // rows are exact (N % BM == 0)
      gload_lds16(A + (size_t)arow * D + kss * BK + lvec_st * 16,
                  dst + ch * 1024 + lane * 16);
    }
  };

  // ---- prologue: issue stage(0); first loop iteration waits it ----
  stageB(chunk * BN, 0, smB[0]);
  stageA(0, smA[0]);

  int cur = 0;
  for (int si = 0; si < nsub; ++si) {
    const int col0 = (chunk + si * NC) * BN;
    floatx4 acc[4][8];
#pragma unroll
    for (int i = 0; i < 4; ++i)
#pragma unroll
      for (int j = 0; j < 8; ++j) acc[i][j] = floatx4{0.f, 0.f, 0.f, 0.f};

#pragma unroll 1  // keep body small: full unroll spills acc (round-2 lesson)
    for (int ks = 0; ks < D / BK; ++ks) {
      const int ksn = (ks + 1) & 7;
      // ks==7 stages the NEXT tile's ks=0 (past-the-end cols clamp harmlessly
      // on the final tile; nobody reads that buffer afterwards).
      const int col0n = (ks == 7) ? col0 + NC * BN : col0;

      // ---- 1. issue next step's staging (8 gload_lds/wave, zero VGPR) ----
      stageB(col0n, ksn, smB[cur ^ 1]);
      stageA(ksn, smA[cur ^ 1]);

      // ---- 2. counted wait: ONLY stage(g) drained; barrier-1 ----
      __builtin_amdgcn_sched_barrier(0);
      asm volatile("s_waitcnt vmcnt(8)" ::: "memory");
      __builtin_amdgcn_sched_barrier(0);
      __builtin_amdgcn_s_barrier();

      // ---- 3. compute on current buffers ----
      const char* bA = smA[cur];
      const char* bB = smB[cur];
      int8v af[4];
#pragma unroll
      for (int i = 0; i < 4; ++i) {
        const int r = wr * 64 + i * 16 + l16;
        const char* base = bA + r * 128;
        const int4 lo = *(const int4*)(base + (((quad * 2) ^ (r & 7)) * 16));
        const int4 hi =
            *(const int4*)(base + (((quad * 2 + 1) ^ (r & 7)) * 16));
        af[i][0] = lo.x; af[i][1] = lo.y; af[i][2] = lo.z; af[i][3] = lo.w;
        af[i][4] = hi.x; af[i][5] = hi.y; af[i][6] = hi.z; af[i][7] = hi.w;
      }
#pragma unroll
      for (int jh = 0; jh < 2; ++jh) {  // halves cap live bf regs at 32
        int8v bf[4];
#pragma unroll
        for (int jj = 0; jj < 4; ++jj) {
          const int cr = wc * 128 + (jh * 4 + jj) * 16 + l16;
          const char* base = bB + cr * 128;
          const int4 lo =
              *(const int4*)(base + (((quad * 2) ^ (cr & 7)) * 16));
          const int4 hi =
              *(const int4*)(base + (((quad * 2 + 1) ^ (cr & 7)) * 16));
          bf[jj][0] = lo.x; bf[jj][1] = lo.y; bf[jj][2] = lo.z; bf[jj][3] = lo.w;
          bf[jj][4] = hi.x; bf[jj][5] = hi.y; bf[jj][6] = hi.z; bf[jj][7] = hi.w;
        }
        __builtin_amdgcn_s_setprio(1);
#pragma unroll
        for (int jj = 0; jj < 4; ++jj)
#pragma unroll
          for (int i = 0; i < 4; ++i)
            acc[i][jh * 4 + jj] =
                __builtin_amdgcn_mfma_scale_f32_16x16x128_f8f6f4(
                    af[i], bf[jj], acc[i][jh * 4 + jj], 0, 0,  // fp8 both
                    0, 0x7F7F7F7F, 0, 0x7F7F7F7F);             // scales = 2^0
        __builtin_amdgcn_s_setprio(0);
      }

      // ---- 4. barrier-2: close reads of buf[cur] before next-step stage ----
      asm volatile("s_waitcnt lgkmcnt(0)" ::: "memory");
      __builtin_amdgcn_sched_barrier(0);
      __builtin_amdgcn_s_barrier();
      cur ^= 1;
    }

    // ---- per-tile online update (register-only; overlaps in-flight stage) --
    {
      const bool edge = (col0 + BN > V);  // wave-uniform (last tile only)
#pragma unroll
      for (int i = 0; i < 4; ++i) {
#pragma unroll
        for (int reg = 0; reg < 4; ++reg) {
          float v[8];
#pragma unroll
          for (int j = 0; j < 8; ++j) v[j] = acc[i][j][reg];
          if (edge) {
            const int cb = col0 + wc * 128 + l16;
#pragma unroll
            for (int j = 0; j < 8; ++j)
              if (cb + j * 16 >= V) v[j] = -INFINITY;
          }
          float mx = v[0];
#pragma unroll
          for (int j = 1; j < 8; ++j) mx = fmaxf(mx, v[j]);
          const int x = i * 4 + reg;
          const float nm = fmaxf(rm[x], mx);
          float s = rs[x] * fexp2(rm[x] - nm);
#pragma unroll
          for (int j = 0; j < 8; ++j) s += fexp2(v[j] - nm);
          rs[x] = s;
          rm[x] = nm;
        }
      }
    }
  }

  // ---- once-per-kernel reduction: butterfly over 16 lanes per row ----
#pragma unroll
  for (int x = 0; x < 16; ++x) {
    float m = rm[x], s = rs[x];
#pragma unroll
    for (int d = 1; d < 16; d <<= 1) {
      const float om = __shfl_xor(m, d, 64);
      const float os = __shfl_xor(s, d, 64);
      const float nm = fmaxf(m, om);
      s = s * fexp2(m - nm) + os * fexp2(om - nm);
      m = nm;
    }
    if (l16 == 0) {
      const int i = x >> 2, reg = x & 3;
      const int rloc = wr * 64 + i * 16 + quad * 4 + reg;  // 0..255
      red_m[wc][rloc] = m;
      red_s[wc][rloc] = s;
    }
  }
  __syncthreads();  // full drain once per kernel (also retires dangling stage)
  if (tid < BM) {  // merge the two column-half groups, write chunk partials
    const float m0 = red_m[0][tid], s0 = red_s[0][tid];
    const float m1 = red_m[1][tid], s1 = red_s[1][tid];
    const float tm = fmaxf(m0, m1);
    const float ts = s0 * fexp2(m0 - tm) + s1 * fexp2(m1 - tm);
    m_part[(size_t)chunk * N + row0 + tid] = tm;
    s_part[(size_t)chunk * N + row0 + tid] = ts;
  }
}

// ---------------- finalize: merge chunk partials, subtract target, mean -----
__global__ void finalize1_kernel(const float* __restrict__ m_part,
                                 const float* __restrict__ s_part,
                                 const float* __restrict__ tgt,
                                 const int* __restrict__ t,
                                 double* __restrict__ fin) {
  const int tid = threadIdx.x;
  const int row = blockIdx.x * 256 + tid;
  float M = -1e30f;
#pragma unroll
  for (int ch = 0; ch < NC; ++ch) M = fmaxf(M, m_part[ch * N + row]);
  float S = 0.f;
#pragma unroll
  for (int ch = 0; ch < NC; ++ch)
    S += s_part[ch * N + row] * fexp2(m_part[ch * N + row] - M);
  const float lse = LN2 * (M + log2f(S));  // back to natural-log space
  double nll = 0.0;
  double cnt = 0.0;
  if (t[row] != IGNORE_INDEX) {
    nll = (double)(lse - tgt[row]);
    cnt = 1.0;
  }
  __shared__ double sacc[256];
  __shared__ double scnt[256];
  sacc[tid] = nll;
  scnt[tid] = cnt;
  __syncthreads();
  for (int s = 128; s > 0; s >>= 1) {
    if (tid < s) {
      sacc[tid] += sacc[tid + s];
      scnt[tid] += scnt[tid + s];
    }
    __syncthreads();
  }
  if (tid == 0) {
    fin[blockIdx.x * 2] = sacc[0];
    fin[blockIdx.x * 2 + 1] = scnt[0];
  }
}

__global__ void finalize2_kernel(const double* __restrict__ fin,
                                 float* __restrict__ out) {
  const int tid = threadIdx.x;  // 64 threads, 32 active
  __shared__ double sa[64], sc[64];
  sa[tid] = (tid < 32) ? fin[tid * 2] : 0.0;
  sc[tid] = (tid < 32) ? fin[tid * 2 + 1] : 0.0;
  __syncthreads();
  for (int s = 32; s > 0; s >>= 1) {
    if (tid < s) {
      sa[tid] += sa[tid + s];
      sc[tid] += sc[tid + s];
    }
    __syncthreads();
  }
  if (tid == 0) out[0] = (float)(sa[0] / fmax(sc[0], 1.0));
}

extern "C" void kernel_launch(void* const* d_in, const int* in_sizes, int n_in,
                              void* d_out, int out_size, void* d_ws,
                              size_t ws_size, hipStream_t stream) {
  const float* e = (const float*)d_in[0];
  const float* c = (const float*)d_in[1];
  const int* t = (const int*)d_in[2];
  float* out = (float*)d_out;

  char* ws = (char*)d_ws;
  unsigned char* e8 = (unsigned char*)ws;  // 8 MB (log2e-scaled fp8)
  size_t off = (size_t)N * D;
  unsigned char* c8 = (unsigned char*)(ws + off);  // 51.5 MB
  off += (size_t)V * D;
  off = (off + 255) & ~(size_t)255;
  float* tgt = (float*)(ws + off);
  off += (size_t)N * 4;
  float* m_part = (float*)(ws + off);
  off += (size_t)NC * N * 4;
  float* s_part = (float*)(ws + off);
  off += (size_t)NC * N * 4;
  double* fin = (double*)(ws + off);
  off += 32 * 2 * sizeof(double);  // total ~61 MB of d_ws

  prep_kernel<<<EB + CB + TGT_BLOCKS, 256, 0, stream>>>(
      e, c, t, (unsigned int*)e8, (unsigned int*)c8, tgt);
  gemm_lse_kernel<<<dim3(NC, N / BM), 512, 0, stream>>>(e8, c8, m_part,
                                                        s_part);
  finalize1_kernel<<<32, 256, 0, stream>>>(m_part, s_part, tgt, t, fin);
  finalize2_kernel<<<1, 64, 0, stream>>>(fin, out);
}